// Round 1
// baseline (426.582 us; speedup 1.0000x reference)
//
#include <hip/hip_runtime.h>

#define N_NODES 16384
#define N_EDGES 262144
#define D 256
#define B_GRAPHS 32
#define NODES_PER_GRAPH 512   // N_NODES / B_GRAPHS

// ---------------------------------------------------------------------------
// CSR build: in-degree count -> exclusive scan -> atomic fill
// ---------------------------------------------------------------------------
__global__ __launch_bounds__(256) void count_deg_kernel(const int* __restrict__ edge,
                                                        int* __restrict__ deg) {
    int e = blockIdx.x * 256 + threadIdx.x;
    if (e < N_EDGES) {
        int dst = edge[N_EDGES + e];
        atomicAdd(&deg[dst], 1);
    }
}

__global__ __launch_bounds__(256) void scan_kernel(const int* __restrict__ deg,
                                                   int* __restrict__ row_ptr,
                                                   int* __restrict__ cursor,
                                                   float* __restrict__ inv_deg) {
    int t = threadIdx.x;
    int base = t * 64;                 // 256 threads x 64 = 16384
    int s = 0;
    for (int i = 0; i < 64; ++i) s += deg[base + i];
    __shared__ int sums[256];
    sums[t] = s;
    __syncthreads();
    for (int off = 1; off < 256; off <<= 1) {
        int v = (t >= off) ? sums[t - off] : 0;
        __syncthreads();
        sums[t] += v;
        __syncthreads();
    }
    int prefix = (t == 0) ? 0 : sums[t - 1];
    for (int i = 0; i < 64; ++i) {
        int d = deg[base + i];
        row_ptr[base + i] = prefix;
        cursor[base + i]  = prefix;
        inv_deg[base + i] = 1.0f / (float)(d < 1 ? 1 : d);
        prefix += d;
    }
    if (t == 255) row_ptr[N_NODES] = prefix;
}

__global__ __launch_bounds__(256) void fill_kernel(const int* __restrict__ edge,
                                                   int* __restrict__ cursor,
                                                   int* __restrict__ col) {
    int e = blockIdx.x * 256 + threadIdx.x;
    if (e < N_EDGES) {
        int src = edge[e];
        int dst = edge[N_EDGES + e];
        int pos = atomicAdd(&cursor[dst], 1);
        col[pos] = src;
    }
}

// ---------------------------------------------------------------------------
// Mean aggregation: one 64-lane wave per destination node.
// lane handles float4 at column lane*4 (64*4 = 256 = D).
// ---------------------------------------------------------------------------
__global__ __launch_bounds__(256) void agg_kernel(const float* __restrict__ X,
                                                  const int* __restrict__ row_ptr,
                                                  const int* __restrict__ col,
                                                  const float* __restrict__ inv_deg,
                                                  float* __restrict__ Agg) {
    int node = blockIdx.x * 4 + (threadIdx.x >> 6);
    int lane = threadIdx.x & 63;
    int start = row_ptr[node];
    int end   = row_ptr[node + 1];
    float4 acc = make_float4(0.f, 0.f, 0.f, 0.f);
    for (int e0 = start; e0 < end; e0 += 64) {
        int cnt = end - e0; if (cnt > 64) cnt = 64;
        int my = (lane < cnt) ? col[e0 + lane] : 0;
        for (int j = 0; j < cnt; ++j) {
            int s = __shfl(my, j);
            float4 v = *(const float4*)&X[(size_t)s * D + lane * 4];
            acc.x += v.x; acc.y += v.y; acc.z += v.z; acc.w += v.w;
        }
    }
    float id = inv_deg[node];
    acc.x *= id; acc.y *= id; acc.z *= id; acc.w *= id;
    *(float4*)&Agg[(size_t)node * D + lane * 4] = acc;
}

// ---------------------------------------------------------------------------
// Dual GEMM per layer: Xout = Xin @ Wr + Agg @ Wl + bias       [16384,256]
// Block: 256 threads, tile 64 rows x 256 cols, BK=32.
// Thread (tr,tc): tr=tid>>5 (8 row groups of 8), tc=tid&31; cols = tc + 32*j.
// Bs read bank = (4*kk + tc) % 32 -> conflict-free. As read: 2-way broadcast.
// ---------------------------------------------------------------------------
#define BM 64
#define BK 32
__global__ __launch_bounds__(256) void gemm_kernel(const float* __restrict__ Xin,
                                                   const float* __restrict__ Agg,
                                                   const float* __restrict__ Wr,
                                                   const float* __restrict__ Wl,
                                                   const float* __restrict__ bias,
                                                   float* __restrict__ Xout) {
    __shared__ float As[BM][BK + 4];   // [64][36], pad keeps stores ~conflict-light
    __shared__ float Bs[BK][D + 4];    // [32][260], read bank = (4kk+tc)%32

    const int tid = threadIdx.x;
    const int m0  = blockIdx.x * BM;
    const int tr  = tid >> 5;
    const int tc  = tid & 31;

    float acc[8][8];
    #pragma unroll
    for (int i = 0; i < 8; ++i)
        #pragma unroll
        for (int j = 0; j < 8; ++j) acc[i][j] = 0.f;

    for (int phase = 0; phase < 2; ++phase) {
        const float* A = phase ? Agg : Xin;
        const float* W = phase ? Wl  : Wr;
        for (int k0 = 0; k0 < D; k0 += BK) {
            __syncthreads();  // protect LDS from previous iteration's readers
            // stage A tile: 64 rows x 32 k = 512 float4
            #pragma unroll
            for (int i = 0; i < 2; ++i) {
                int idx = tid + i * 256;
                int row = idx >> 3, c4 = idx & 7;
                float4 v = *(const float4*)&A[(size_t)(m0 + row) * D + k0 + c4 * 4];
                *(float4*)&As[row][c4 * 4] = v;
            }
            // stage B tile: 32 k x 256 cols = 2048 float4
            #pragma unroll
            for (int i = 0; i < 8; ++i) {
                int idx = tid + i * 256;
                int kk = idx >> 6, c4 = idx & 63;
                float4 v = *(const float4*)&W[(size_t)(k0 + kk) * D + c4 * 4];
                *(float4*)&Bs[kk][c4 * 4] = v;
            }
            __syncthreads();
            #pragma unroll 4
            for (int kk = 0; kk < BK; ++kk) {
                float a[8], b[8];
                #pragma unroll
                for (int i = 0; i < 8; ++i) a[i] = As[tr * 8 + i][kk];
                #pragma unroll
                for (int j = 0; j < 8; ++j) b[j] = Bs[kk][tc + 32 * j];
                #pragma unroll
                for (int i = 0; i < 8; ++i)
                    #pragma unroll
                    for (int j = 0; j < 8; ++j)
                        acc[i][j] += a[i] * b[j];
            }
        }
    }

    #pragma unroll
    for (int j = 0; j < 8; ++j) {
        float bv = bias[tc + 32 * j];
        #pragma unroll
        for (int i = 0; i < 8; ++i) {
            Xout[(size_t)(m0 + tr * 8 + i) * D + tc + 32 * j] = acc[i][j] + bv;
        }
    }
}

// ---------------------------------------------------------------------------
// MLP head: one block per graph; h = root node row; 2x ReLU GEMV + linear out
// ---------------------------------------------------------------------------
__global__ __launch_bounds__(256) void head_kernel(const float* __restrict__ X,
                                                   const float* __restrict__ Wh,
                                                   const float* __restrict__ bh,
                                                   const float* __restrict__ Wo,
                                                   const float* __restrict__ bo,
                                                   float* __restrict__ out) {
    int b = blockIdx.x, t = threadIdx.x;
    __shared__ float h[D];
    h[t] = X[(size_t)(b * NODES_PER_GRAPH) * D + t];
    __syncthreads();
    for (int l = 0; l < 2; ++l) {
        float acc = bh[l * D + t];
        const float* W = Wh + (size_t)l * D * D;
        #pragma unroll 8
        for (int k = 0; k < D; ++k) acc += h[k] * W[(size_t)k * D + t];
        __syncthreads();
        h[t] = fmaxf(acc, 0.0f);
        __syncthreads();
    }
    float acc = bo[t];
    #pragma unroll 8
    for (int k = 0; k < D; ++k) acc += h[k] * Wo[(size_t)k * D + t];
    out[(size_t)b * D + t] = acc;
}

// ---------------------------------------------------------------------------
extern "C" void kernel_launch(void* const* d_in, const int* in_sizes, int n_in,
                              void* d_out, int out_size, void* d_ws, size_t ws_size,
                              hipStream_t stream) {
    const float* x    = (const float*)d_in[0];
    const int*   edge = (const int*)d_in[1];   // [2, N_EDGES], values < 16384
    const float* Wl   = (const float*)d_in[2];
    const float* bl   = (const float*)d_in[3];
    const float* Wr   = (const float*)d_in[4];
    const float* Wh   = (const float*)d_in[5];
    const float* bh   = (const float*)d_in[6];
    const float* Wo   = (const float*)d_in[7];
    const float* bo   = (const float*)d_in[8];
    float* out = (float*)d_out;

    char* w = (char*)d_ws;
    auto alloc = [&](size_t bytes) {
        char* p = w;
        w += (bytes + 255) & ~(size_t)255;
        return p;
    };
    int*   deg     = (int*)  alloc((size_t)N_NODES * 4);
    int*   row_ptr = (int*)  alloc((size_t)(N_NODES + 1) * 4);
    int*   cursor  = (int*)  alloc((size_t)N_NODES * 4);
    float* invdeg  = (float*)alloc((size_t)N_NODES * 4);
    int*   col     = (int*)  alloc((size_t)N_EDGES * 4);
    float* agg     = (float*)alloc((size_t)N_NODES * D * 4);
    float* xb0     = (float*)alloc((size_t)N_NODES * D * 4);
    float* xb1     = (float*)alloc((size_t)N_NODES * D * 4);

    hipMemsetAsync(deg, 0, (size_t)N_NODES * 4, stream);
    count_deg_kernel<<<N_EDGES / 256, 256, 0, stream>>>(edge, deg);
    scan_kernel<<<1, 256, 0, stream>>>(deg, row_ptr, cursor, invdeg);
    fill_kernel<<<N_EDGES / 256, 256, 0, stream>>>(edge, cursor, col);

    const float* xin = x;
    float* bufs[2] = {xb0, xb1};
    for (int l = 0; l < 3; ++l) {
        agg_kernel<<<N_NODES / 4, 256, 0, stream>>>(xin, row_ptr, col, invdeg, agg);
        float* xout = bufs[l & 1];
        gemm_kernel<<<N_NODES / BM, 256, 0, stream>>>(xin, agg,
                                                      Wr + (size_t)l * D * D,
                                                      Wl + (size_t)l * D * D,
                                                      bl + (size_t)l * D,
                                                      xout);
        xin = xout;
    }
    head_kernel<<<B_GRAPHS, 256, 0, stream>>>(xin, Wh, bh, Wo, bo, out);
}

// Round 2
// 258.635 us; speedup vs baseline: 1.6494x; 1.6494x over previous
//
#include <hip/hip_runtime.h>

#define N_NODES 16384
#define N_EDGES 262144
#define D 256
#define B_GRAPHS 32
#define NODES_PER_GRAPH 512   // N_NODES / B_GRAPHS

typedef __attribute__((ext_vector_type(8)))  short bf16x8;
typedef __attribute__((ext_vector_type(16))) float f32x16;
typedef __attribute__((ext_vector_type(8)))  unsigned short u16x8;

static __device__ __forceinline__ unsigned short f2bf(float f) {
    unsigned int u = __float_as_uint(f);
    unsigned int r = (u + 0x7FFFu + ((u >> 16) & 1u)) >> 16;   // RNE
    return (unsigned short)r;
}
static __device__ __forceinline__ float bf2f(unsigned short h) {
    return __uint_as_float(((unsigned int)h) << 16);
}

// ---------------------------------------------------------------------------
// CSR build: in-degree count -> exclusive scan -> atomic fill
// ---------------------------------------------------------------------------
__global__ __launch_bounds__(256) void count_deg_kernel(const int* __restrict__ edge,
                                                        int* __restrict__ deg) {
    int e = blockIdx.x * 256 + threadIdx.x;
    if (e < N_EDGES) {
        int dst = edge[N_EDGES + e];
        atomicAdd(&deg[dst], 1);
    }
}

__global__ __launch_bounds__(256) void scan_kernel(const int* __restrict__ deg,
                                                   int* __restrict__ row_ptr,
                                                   int* __restrict__ cursor,
                                                   float* __restrict__ inv_deg) {
    int t = threadIdx.x;
    int base = t * 64;                 // 256 threads x 64 = 16384
    int s = 0;
    for (int i = 0; i < 64; ++i) s += deg[base + i];
    __shared__ int sums[256];
    sums[t] = s;
    __syncthreads();
    for (int off = 1; off < 256; off <<= 1) {
        int v = (t >= off) ? sums[t - off] : 0;
        __syncthreads();
        sums[t] += v;
        __syncthreads();
    }
    int prefix = (t == 0) ? 0 : sums[t - 1];
    for (int i = 0; i < 64; ++i) {
        int d = deg[base + i];
        row_ptr[base + i] = prefix;
        cursor[base + i]  = prefix;
        inv_deg[base + i] = 1.0f / (float)(d < 1 ? 1 : d);
        prefix += d;
    }
    if (t == 255) row_ptr[N_NODES] = prefix;
}

__global__ __launch_bounds__(256) void fill_kernel(const int* __restrict__ edge,
                                                   int* __restrict__ cursor,
                                                   int* __restrict__ col) {
    int e = blockIdx.x * 256 + threadIdx.x;
    if (e < N_EDGES) {
        int src = edge[e];
        int dst = edge[N_EDGES + e];
        int pos = atomicAdd(&cursor[dst], 1);
        col[pos] = src;
    }
}

// ---------------------------------------------------------------------------
// Mean aggregation: one 64-lane wave per destination node.
// ---------------------------------------------------------------------------
__global__ __launch_bounds__(256) void agg_kernel(const float* __restrict__ X,
                                                  const int* __restrict__ row_ptr,
                                                  const int* __restrict__ col,
                                                  const float* __restrict__ inv_deg,
                                                  float* __restrict__ Agg) {
    int node = blockIdx.x * 4 + (threadIdx.x >> 6);
    int lane = threadIdx.x & 63;
    int start = row_ptr[node];
    int end   = row_ptr[node + 1];
    float4 acc = make_float4(0.f, 0.f, 0.f, 0.f);
    for (int e0 = start; e0 < end; e0 += 64) {
        int cnt = end - e0; if (cnt > 64) cnt = 64;
        int my = (lane < cnt) ? col[e0 + lane] : 0;
        for (int j = 0; j < cnt; ++j) {
            int s = __shfl(my, j);
            float4 v = *(const float4*)&X[(size_t)s * D + lane * 4];
            acc.x += v.x; acc.y += v.y; acc.z += v.z; acc.w += v.w;
        }
    }
    float id = inv_deg[node];
    acc.x *= id; acc.y *= id; acc.z *= id; acc.w *= id;
    *(float4*)&Agg[(size_t)node * D + lane * 4] = acc;
}

// ---------------------------------------------------------------------------
// W pre-transpose + split: Wt_hi[n][k], Wt_lo[n][k] (bf16) from W[k][n] f32.
// 96 blocks: 6 matrices x 16 (64x64) subtiles.
// ---------------------------------------------------------------------------
__global__ __launch_bounds__(256) void transpose_w_kernel(
    const float* __restrict__ Wl, const float* __restrict__ Wr,
    unsigned short* __restrict__ WtL_hi, unsigned short* __restrict__ WtL_lo,
    unsigned short* __restrict__ WtR_hi, unsigned short* __restrict__ WtR_lo)
{
    __shared__ float S[64][68];
    int bid = blockIdx.x;
    int mat = bid / 16, sub = bid % 16;
    int kt = (sub >> 2) * 64, nt = (sub & 3) * 64;
    const float* src      = (mat < 3) ? Wl + (size_t)mat * 65536 : Wr + (size_t)(mat - 3) * 65536;
    unsigned short* dhi   = (mat < 3) ? WtL_hi + (size_t)mat * 65536 : WtR_hi + (size_t)(mat - 3) * 65536;
    unsigned short* dlo   = (mat < 3) ? WtL_lo + (size_t)mat * 65536 : WtR_lo + (size_t)(mat - 3) * 65536;
    int t = threadIdx.x;
    int r = t >> 2, c0 = (t & 3) * 16;
    #pragma unroll
    for (int j = 0; j < 4; ++j) {
        float4 v = *(const float4*)&src[(size_t)(kt + r) * 256 + nt + c0 + j * 4];
        *(float4*)&S[r][c0 + j * 4] = v;
    }
    __syncthreads();
    int n = t >> 2, kc = (t & 3) * 16;
    u16x8 h0, h1, l0, l1;
    #pragma unroll
    for (int j = 0; j < 8; ++j) {
        float x = S[kc + j][n];
        unsigned short h = f2bf(x);
        h0[j] = h; l0[j] = f2bf(x - bf2f(h));
        float y = S[kc + 8 + j][n];
        unsigned short g = f2bf(y);
        h1[j] = g; l1[j] = f2bf(y - bf2f(g));
    }
    size_t o = (size_t)(nt + n) * 256 + kt + kc;
    *(u16x8*)&dhi[o] = h0; *(u16x8*)&dhi[o + 8] = h1;
    *(u16x8*)&dlo[o] = l0; *(u16x8*)&dlo[o + 8] = l1;
}

// ---------------------------------------------------------------------------
// MFMA dual GEMM, split-bf16 3-pass:
//   Xout = Xin@Wr + Agg@Wl + bias   (each product = Ahi@Whi + Alo@Whi + Ahi@Wlo)
// Tile 64x128, 4 waves (2x2, each 32x64), BK=32, mfma_f32_32x32x16_bf16.
// A converted f32->hi/lo bf16 while staging to LDS. W pre-split, [n][k] layout.
// LDS rows padded to 40 ushorts: b128 reads hit the 8-clk bank floor.
// ---------------------------------------------------------------------------
#define GBM 64
#define GBN 128
#define GBK 32
#define LSTR 40

__global__ __launch_bounds__(256) void gemm_mfma_kernel(
    const float* __restrict__ Xin,
    const float* __restrict__ Agg,
    const unsigned short* __restrict__ WtR_hi, const unsigned short* __restrict__ WtR_lo,
    const unsigned short* __restrict__ WtL_hi, const unsigned short* __restrict__ WtL_lo,
    const float* __restrict__ bias,
    float* __restrict__ Xout)
{
    __shared__ unsigned short Ahi[GBM][LSTR];
    __shared__ unsigned short Alo[GBM][LSTR];
    __shared__ unsigned short Bhi[GBN][LSTR];
    __shared__ unsigned short Blo[GBN][LSTR];

    const int tid  = threadIdx.x;
    const int wave = tid >> 6, lane = tid & 63;
    const int wm = wave >> 1, wn = wave & 1;          // 2x2 wave grid
    const int bid = blockIdx.x;
    const int m0 = (bid >> 1) * GBM;
    const int n0 = (bid & 1) * GBN;

    f32x16 acc[2];
    #pragma unroll
    for (int j = 0; j < 16; ++j) { acc[0][j] = 0.f; acc[1][j] = 0.f; }

    // staging indices (computed once)
    const int ea   = tid * 2;             // A: 2 consecutive float4 per thread
    const int arow = ea >> 3;             // 8 float4 per 32-float row
    const int ac4  = ea & 7;
    const int wrow0 = (tid * 2) >> 2;     // W: 2 u16x8 per thread per array
    const int wq0   = (tid * 2) & 3;
    const int wrow1 = (tid * 2 + 1) >> 2;
    const int wq1   = (tid * 2 + 1) & 3;

    // compute indices
    const int r   = lane & 31;
    const int kh  = (lane >> 5) * 8;
    const int ar  = wm * 32 + r;
    const int bc0 = wn * 64 + r;

    for (int phase = 0; phase < 2; ++phase) {
        const float* A = phase ? Agg : Xin;
        const unsigned short* Whi = phase ? WtL_hi : WtR_hi;
        const unsigned short* Wlo = phase ? WtL_lo : WtR_lo;
        for (int k0 = 0; k0 < D; k0 += GBK) {
            __syncthreads();
            // --- stage A tile 64x32 f32 -> hi/lo bf16 ---
            {
                const float* ap = &A[(size_t)(m0 + arow) * D + k0 + ac4 * 4];
                float4 v0 = ((const float4*)ap)[0];
                float4 v1 = ((const float4*)ap)[1];
                float xs[8] = {v0.x, v0.y, v0.z, v0.w, v1.x, v1.y, v1.z, v1.w};
                u16x8 h, l;
                #pragma unroll
                for (int j = 0; j < 8; ++j) {
                    unsigned short hh = f2bf(xs[j]);
                    h[j] = hh;
                    l[j] = f2bf(xs[j] - bf2f(hh));
                }
                *(u16x8*)&Ahi[arow][ac4 * 4] = h;
                *(u16x8*)&Alo[arow][ac4 * 4] = l;
            }
            // --- stage W tiles 128x32 bf16 (hi & lo) ---
            {
                u16x8 a = *(const u16x8*)&Whi[(size_t)(n0 + wrow0) * D + k0 + wq0 * 8];
                u16x8 b = *(const u16x8*)&Whi[(size_t)(n0 + wrow1) * D + k0 + wq1 * 8];
                u16x8 c = *(const u16x8*)&Wlo[(size_t)(n0 + wrow0) * D + k0 + wq0 * 8];
                u16x8 d = *(const u16x8*)&Wlo[(size_t)(n0 + wrow1) * D + k0 + wq1 * 8];
                *(u16x8*)&Bhi[wrow0][wq0 * 8] = a;
                *(u16x8*)&Bhi[wrow1][wq1 * 8] = b;
                *(u16x8*)&Blo[wrow0][wq0 * 8] = c;
                *(u16x8*)&Blo[wrow1][wq1 * 8] = d;
            }
            __syncthreads();
            // --- MFMA: 2 k-steps of 16, 3 split-combos, 2 n-frags ---
            #pragma unroll
            for (int s = 0; s < 2; ++s) {
                const int ko = s * 16 + kh;
                bf16x8 ah  = *(const bf16x8*)&Ahi[ar][ko];
                bf16x8 al  = *(const bf16x8*)&Alo[ar][ko];
                bf16x8 bh0 = *(const bf16x8*)&Bhi[bc0][ko];
                bf16x8 bh1 = *(const bf16x8*)&Bhi[bc0 + 32][ko];
                bf16x8 bl0 = *(const bf16x8*)&Blo[bc0][ko];
                bf16x8 bl1 = *(const bf16x8*)&Blo[bc0 + 32][ko];
                acc[0] = __builtin_amdgcn_mfma_f32_32x32x16_bf16(ah, bh0, acc[0], 0, 0, 0);
                acc[1] = __builtin_amdgcn_mfma_f32_32x32x16_bf16(ah, bh1, acc[1], 0, 0, 0);
                acc[0] = __builtin_amdgcn_mfma_f32_32x32x16_bf16(al, bh0, acc[0], 0, 0, 0);
                acc[1] = __builtin_amdgcn_mfma_f32_32x32x16_bf16(al, bh1, acc[1], 0, 0, 0);
                acc[0] = __builtin_amdgcn_mfma_f32_32x32x16_bf16(ah, bl0, acc[0], 0, 0, 0);
                acc[1] = __builtin_amdgcn_mfma_f32_32x32x16_bf16(ah, bl1, acc[1], 0, 0, 0);
            }
        }
    }

    // epilogue: C/D layout col=lane&31, row=(reg&3)+8*(reg>>2)+4*(lane>>5)
    const int crow0 = m0 + wm * 32 + 4 * (lane >> 5);
    const int ccol0 = n0 + wn * 64 + (lane & 31);
    #pragma unroll
    for (int fn = 0; fn < 2; ++fn) {
        const int col = ccol0 + fn * 32;
        const float bv = bias[col];
        #pragma unroll
        for (int reg = 0; reg < 16; ++reg) {
            const int row = crow0 + (reg & 3) + 8 * (reg >> 2);
            Xout[(size_t)row * D + col] = acc[fn][reg] + bv;
        }
    }
}

// ---------------------------------------------------------------------------
// MLP head: one block per graph
// ---------------------------------------------------------------------------
__global__ __launch_bounds__(256) void head_kernel(const float* __restrict__ X,
                                                   const float* __restrict__ Wh,
                                                   const float* __restrict__ bh,
                                                   const float* __restrict__ Wo,
                                                   const float* __restrict__ bo,
                                                   float* __restrict__ out) {
    int b = blockIdx.x, t = threadIdx.x;
    __shared__ float h[D];
    h[t] = X[(size_t)(b * NODES_PER_GRAPH) * D + t];
    __syncthreads();
    for (int l = 0; l < 2; ++l) {
        float acc = bh[l * D + t];
        const float* W = Wh + (size_t)l * D * D;
        #pragma unroll 8
        for (int k = 0; k < D; ++k) acc += h[k] * W[(size_t)k * D + t];
        __syncthreads();
        h[t] = fmaxf(acc, 0.0f);
        __syncthreads();
    }
    float acc = bo[t];
    #pragma unroll 8
    for (int k = 0; k < D; ++k) acc += h[k] * Wo[(size_t)k * D + t];
    out[(size_t)b * D + t] = acc;
}

// ---------------------------------------------------------------------------
extern "C" void kernel_launch(void* const* d_in, const int* in_sizes, int n_in,
                              void* d_out, int out_size, void* d_ws, size_t ws_size,
                              hipStream_t stream) {
    const float* x    = (const float*)d_in[0];
    const int*   edge = (const int*)d_in[1];
    const float* Wl   = (const float*)d_in[2];
    const float* bl   = (const float*)d_in[3];
    const float* Wr   = (const float*)d_in[4];
    const float* Wh   = (const float*)d_in[5];
    const float* bh   = (const float*)d_in[6];
    const float* Wo   = (const float*)d_in[7];
    const float* bo   = (const float*)d_in[8];
    float* out = (float*)d_out;

    char* w = (char*)d_ws;
    auto alloc = [&](size_t bytes) {
        char* p = w;
        w += (bytes + 255) & ~(size_t)255;
        return p;
    };
    int*   deg     = (int*)  alloc((size_t)N_NODES * 4);
    int*   row_ptr = (int*)  alloc((size_t)(N_NODES + 1) * 4);
    int*   cursor  = (int*)  alloc((size_t)N_NODES * 4);
    float* invdeg  = (float*)alloc((size_t)N_NODES * 4);
    int*   col     = (int*)  alloc((size_t)N_EDGES * 4);
    float* agg     = (float*)alloc((size_t)N_NODES * D * 4);
    float* xb0     = (float*)alloc((size_t)N_NODES * D * 4);
    float* xb1     = (float*)alloc((size_t)N_NODES * D * 4);
    unsigned short* WtL_hi = (unsigned short*)alloc((size_t)3 * 65536 * 2);
    unsigned short* WtL_lo = (unsigned short*)alloc((size_t)3 * 65536 * 2);
    unsigned short* WtR_hi = (unsigned short*)alloc((size_t)3 * 65536 * 2);
    unsigned short* WtR_lo = (unsigned short*)alloc((size_t)3 * 65536 * 2);

    transpose_w_kernel<<<96, 256, 0, stream>>>(Wl, Wr, WtL_hi, WtL_lo, WtR_hi, WtR_lo);

    hipMemsetAsync(deg, 0, (size_t)N_NODES * 4, stream);
    count_deg_kernel<<<N_EDGES / 256, 256, 0, stream>>>(edge, deg);
    scan_kernel<<<1, 256, 0, stream>>>(deg, row_ptr, cursor, invdeg);
    fill_kernel<<<N_EDGES / 256, 256, 0, stream>>>(edge, cursor, col);

    const float* xin = x;
    float* bufs[2] = {xb0, xb1};
    for (int l = 0; l < 3; ++l) {
        agg_kernel<<<N_NODES / 4, 256, 0, stream>>>(xin, row_ptr, col, invdeg, agg);
        float* xout = bufs[l & 1];
        gemm_mfma_kernel<<<(N_NODES / GBM) * (D / GBN), 256, 0, stream>>>(
            xin, agg,
            WtR_hi + (size_t)l * 65536, WtR_lo + (size_t)l * 65536,
            WtL_hi + (size_t)l * 65536, WtL_lo + (size_t)l * 65536,
            bl + (size_t)l * D, xout);
        xin = xout;
    }
    head_kernel<<<B_GRAPHS, 256, 0, stream>>>(xin, Wh, bh, Wo, bo, out);
}